// Round 3
// baseline (67982.074 us; speedup 1.0000x reference)
//
#include <hip/hip_runtime.h>

typedef _Float16 f16;
typedef _Float16 f16x2 __attribute__((ext_vector_type(2)));
typedef _Float16 f16x4 __attribute__((ext_vector_type(4)));
typedef _Float16 f16x8 __attribute__((ext_vector_type(8)));
typedef float f32x4 __attribute__((ext_vector_type(4)));
typedef unsigned long long ull;

#define HD 512
#define T_TOT 16384
#define RING 128
#define NWG 32

// ---------------- ws layout (bytes) ----------------
static const size_t O_XC    = 0;                       // 16384*2048 f16  = 64MB
static const size_t O_W1    = 67108864;                // 2048*2048 f16   = 8MB
static const size_t O_WHH   = 75497472;                // 2048*512 f16    = 2MB
static const size_t O_W2    = 77594624;                // 2048*512 f16    = 2MB
static const size_t O_G     = 79691776;                // 16384*2048 f32  = 128MB
static const size_t O_PRING = 213909504;               // 128*256 ull     = 256KB  (gen-tagged packed h)

__device__ __forceinline__ float dot2f(f16x2 a, f16x2 b, float c) {
#if __has_builtin(__builtin_amdgcn_fdot2)
    return __builtin_amdgcn_fdot2(a, b, c, false);
#else
    return fmaf((float)a[0], (float)b[0], fmaf((float)a[1], (float)b[1], c));
#endif
}
__device__ __forceinline__ f16x2 bcf(unsigned int u) { return __builtin_bit_cast(f16x2, u); }

__device__ __forceinline__ float sigf(float x) {
    return 1.0f / (1.0f + __expf(-x));
}
__device__ __forceinline__ float tanhfast(float x) {
    return 1.0f - 2.0f / (__expf(2.0f * x) + 1.0f);
}

// relaxed agent-scope (sc0 sc1: through to L3 coherence point, no inv/wb)
__device__ __forceinline__ ull ld_a64(const ull* p) {
    return __hip_atomic_load(p, __ATOMIC_RELAXED, __HIP_MEMORY_SCOPE_AGENT);
}
__device__ __forceinline__ void st_a64(ull* p, ull v) {
    __hip_atomic_store(p, v, __ATOMIC_RELAXED, __HIP_MEMORY_SCOPE_AGENT);
}

// ---------- convert x,hi -> XC f16 [t=s*64+b][k 0..2048) ----------
__global__ __launch_bounds__(256) void conv_xc(const float* __restrict__ x,
                                               const float* __restrict__ hi,
                                               f16* __restrict__ xc) {
    int gid = blockIdx.x * 256 + threadIdx.x;
    int t = gid >> 9;
    int k = (gid & 511) << 2;
    int b = t & 63, s = t >> 6;
    const float* src = (k < 1024) ? (x  + ((size_t)((b << 8) + s) << 10) + k)
                                  : (hi + ((size_t)((b << 8) + s) << 10) + (k - 1024));
    float4 v = *reinterpret_cast<const float4*>(src);
    f16x4 o = { (_Float16)v.x, (_Float16)v.y, (_Float16)v.z, (_Float16)v.w };
    *reinterpret_cast<f16x4*>(xc + ((size_t)t << 11) + k) = o;
}

// ---------- convert W_ih[:, :2048] -> W1 f16 row-major [j][k] ----------
__global__ __launch_bounds__(256) void conv_w1(const float* __restrict__ wih,
                                               f16* __restrict__ w1) {
    int gid = blockIdx.x * 256 + threadIdx.x;
    int j = gid >> 9;
    int k = (gid & 511) << 2;
    float4 v = *reinterpret_cast<const float4*>(wih + (size_t)j * 2560 + k);
    f16x4 o = { (_Float16)v.x, (_Float16)v.y, (_Float16)v.z, (_Float16)v.w };
    *reinterpret_cast<f16x4*>(w1 + ((size_t)j << 11) + k) = o;
}

// ---------- convert W_hh and W_ih[:, 2048:2560] -> f16 [j][k 0..512) ----------
__global__ __launch_bounds__(256) void conv_wc(const float* __restrict__ whh,
                                               const float* __restrict__ wih,
                                               f16* __restrict__ whhf,
                                               f16* __restrict__ w2f) {
    int gid = blockIdx.x * 256 + threadIdx.x;
    int j = gid >> 7;
    int k = (gid & 127) << 2;
    float4 a = *reinterpret_cast<const float4*>(whh + (size_t)j * 512 + k);
    f16x4 oa = { (_Float16)a.x, (_Float16)a.y, (_Float16)a.z, (_Float16)a.w };
    *reinterpret_cast<f16x4*>(whhf + ((size_t)j << 9) + k) = oa;
    float4 bv = *reinterpret_cast<const float4*>(wih + (size_t)j * 2560 + 2048 + k);
    f16x4 ob = { (_Float16)bv.x, (_Float16)bv.y, (_Float16)bv.z, (_Float16)bv.w };
    *reinterpret_cast<f16x4*>(w2f + ((size_t)j << 9) + k) = ob;
}

// ---------- G = XC @ W1^T + (b_ih+b_hh), f16 MFMA, fp32 out ----------
__global__ __launch_bounds__(256) void gemm_pre(const f16* __restrict__ XC,
                                                const f16* __restrict__ W1,
                                                const float* __restrict__ b_ih,
                                                const float* __restrict__ b_hh,
                                                float* __restrict__ G) {
    int w = threadIdx.x >> 6, l = threadIdx.x & 63;
    int R0 = blockIdx.y * 128 + (w >> 1) * 64;
    int C0 = blockIdx.x * 128 + (w & 1) * 64;
    int lr = l & 15, kb = l >> 4;
    f32x4 acc[4][4] = {};
    const f16* Abase = XC + (size_t)(R0 + lr) * 2048 + kb * 8;
    const f16* Bbase = W1 + (size_t)(C0 + lr) * 2048 + kb * 8;
    for (int kk = 0; kk < 2048; kk += 32) {
        f16x8 av[4], bv[4];
#pragma unroll
        for (int i = 0; i < 4; i++)
            av[i] = *reinterpret_cast<const f16x8*>(Abase + (size_t)(i * 16) * 2048 + kk);
#pragma unroll
        for (int i = 0; i < 4; i++)
            bv[i] = *reinterpret_cast<const f16x8*>(Bbase + (size_t)(i * 16) * 2048 + kk);
#pragma unroll
        for (int fr = 0; fr < 4; fr++)
#pragma unroll
            for (int fc = 0; fc < 4; fc++)
                acc[fr][fc] = __builtin_amdgcn_mfma_f32_16x16x32_f16(av[fr], bv[fc], acc[fr][fc], 0, 0, 0);
    }
#pragma unroll
    for (int fc = 0; fc < 4; fc++) {
        int col = C0 + fc * 16 + lr;
        float bias = b_ih[col] + b_hh[col];
#pragma unroll
        for (int fr = 0; fr < 4; fr++) {
#pragma unroll
            for (int r = 0; r < 4; r++) {
                int row = R0 + fr * 16 + kb * 4 + r;
                G[(size_t)row * 2048 + col] = acc[fr][fc][r] + bias;
            }
        }
    }
}

// ---------- sequential chain: 32 WGs x 512 threads, gen-tagged packed ring ----------
// wave wv: gate g=wv&3, unit-half uh=wv>>2. lane: ul=l&7 (unit), q8=l>>3 (k-eighth).
// Packed ull = [gen16 | h2 | h1 | h0]; weights carry 0 at gen slots.
__global__ __launch_bounds__(512, 1) void lstm_chain(const float* __restrict__ G,
                                                     const f16* __restrict__ Whhf,
                                                     const f16* __restrict__ W2f,
                                                     ull* __restrict__ pring,
                                                     float* __restrict__ out) {
    const int wg = blockIdx.x;
    const int tid = threadIdx.x;
    const int wv = tid >> 6, l = tid & 63;
    const int g = wv & 3, uh = wv >> 2;
    const int q8 = l >> 3, ul = l & 7;
    const int u = uh * 8 + ul;
    const int row = g * 512 + wg * 16 + u;

    // ---- build packed weights (zeros at gen / pad positions), pin in VGPRs ----
    unsigned int wlhh[24], whhh[24], wlw2[24], whw2[24];
    {
        const f16* wb1 = Whhf + (size_t)row * 512;
        const f16* wb2 = W2f + (size_t)row * 512;
#pragma unroll
        for (int s = 0; s < 4; s++)
#pragma unroll
            for (int jj = 0; jj < 6; jj++) {
                int k0 = (q8 * 4 + s) * 16 + 3 * jj;
                f16x2 alo, ahi, blo, bhi;
                alo[0] = wb1[k0]; blo[0] = wb2[k0];
                if (jj < 5) {
                    alo[1] = wb1[k0 + 1]; ahi[0] = wb1[k0 + 2];
                    blo[1] = wb2[k0 + 1]; bhi[0] = wb2[k0 + 2];
                } else {
                    alo[1] = (f16)0; ahi[0] = (f16)0;
                    blo[1] = (f16)0; bhi[0] = (f16)0;
                }
                ahi[1] = (f16)0; bhi[1] = (f16)0;
                wlhh[s * 6 + jj] = __builtin_bit_cast(unsigned int, alo);
                whhh[s * 6 + jj] = __builtin_bit_cast(unsigned int, ahi);
                wlw2[s * 6 + jj] = __builtin_bit_cast(unsigned int, blo);
                whw2[s * 6 + jj] = __builtin_bit_cast(unsigned int, bhi);
            }
#pragma unroll
        for (int i = 0; i < 24; i++)
            asm volatile("" : "+v"(wlhh[i]), "+v"(whhh[i]), "+v"(wlw2[i]), "+v"(whw2[i]));
    }

    __shared__ float part[2][4][16];
    float cst = 0.0f;
    float gv = (l < 8) ? G[row] : 0.0f;           // G[t=0]

    for (int t = 0; t < T_TOT; t++) {
        const int buf = t & 1;
        // prefetch next-step G (consumed next iteration)
        int tn = (t + 1 < T_TOT) ? t + 1 : t;
        float gn = (l < 8) ? G[(size_t)tn * 2048 + row] : 0.0f;

        float a0 = 0.0f, a1 = 0.0f;

        // ---- W2 . h[t-64] : always ready (t<64 reads memset zeros = correct init) ----
        {
            const ull* b2 = pring + (size_t)((t + 64) & (RING - 1)) * 256 + q8 * 32;
#pragma unroll
            for (int i = 0; i < 24; i++) {
                ull v = ld_a64(b2 + (i / 6) * 8 + (i % 6));
                f16x4 hv = __builtin_bit_cast(f16x4, v);
                a0 = dot2f(bcf(wlw2[i]), hv.lo, a0);
                a1 = dot2f(bcf(whw2[i]), hv.hi, a1);
            }
        }

        // ---- poll-on-data: reload until every embedded gen == t ----
        {
            const ull* b1 = pring + (size_t)((t - 1) & (RING - 1)) * 256 + q8 * 32;
            const ull want = (ull)t << 48;
            ull v[24];
            while (true) {
                ull x = 0;
#pragma unroll
                for (int i = 0; i < 24; i++)
                    v[i] = ld_a64(b1 + (i / 6) * 8 + (i % 6));
#pragma unroll
                for (int i = 0; i < 24; i++)
                    x |= v[i] ^ want;
                if (!(x >> 48)) break;
            }
#pragma unroll
            for (int i = 0; i < 24; i++) {
                f16x4 hv = __builtin_bit_cast(f16x4, v[i]);
                a0 = dot2f(bcf(wlhh[i]), hv.lo, a0);
                a1 = dot2f(bcf(whhh[i]), hv.hi, a1);
            }
        }

        float acc = a0 + a1;
        acc += __shfl_xor(acc, 8);
        acc += __shfl_xor(acc, 16);
        acc += __shfl_xor(acc, 32);
        if (l < 8) part[buf][g][uh * 8 + l] = acc + gv;
        gv = gn;
        __syncthreads();

        if (wv == 0) {
            // cell on all 64 lanes: lane = gate (l>>4) x unit (l&15)
            int gg = l >> 4, uu = l & 15;
            float val = part[buf][gg][uu];
            float act = (gg == 2) ? tanhfast(val) : sigf(val);
            float fi = __shfl(act, uu);
            float ff = __shfl(act, uu + 16);
            float fg = __shfl(act, uu + 32);
            float fo = __shfl(act, uu + 48);
            cst = ff * cst + fi * fg;
            float h = fo * tanhfast(cst);
            // publish packed h + gen FIRST (critical), then d_out
            unsigned int hb = (unsigned int)__builtin_bit_cast(unsigned short, (f16)h);
            int i0 = 3 * l, i1 = 3 * l + 1, i2 = 3 * l + 2;
            unsigned int p0 = __shfl((int)hb, i0 < 64 ? i0 : 0);
            unsigned int p1 = __shfl((int)hb, i1 < 64 ? i1 : 0);
            unsigned int p2 = __shfl((int)hb, i2 < 64 ? i2 : 0);
            ull pv = (ull)(p0 & 0xffff) | ((ull)(p1 & 0xffff) << 16) |
                     ((ull)(p2 & 0xffff) << 32) | ((ull)(t + 1) << 48);
            if (l < 6)
                st_a64(pring + (size_t)(t & (RING - 1)) * 256 + wg * 8 + l, pv);
            if (l < 16) {
                int b = t & 63, s = t >> 6;
                out[((size_t)((b << 8) + s)) * 512 + wg * 16 + l] = h;
            }
        }
    }
}

extern "C" void kernel_launch(void* const* d_in, const int* in_sizes, int n_in,
                              void* d_out, int out_size, void* d_ws, size_t ws_size,
                              hipStream_t stream) {
    const float* x    = (const float*)d_in[0];
    const float* hi   = (const float*)d_in[1];
    const float* W_ih = (const float*)d_in[2];
    const float* W_hh = (const float*)d_in[3];
    const float* b_ih = (const float*)d_in[4];
    const float* b_hh = (const float*)d_in[5];

    char* ws = (char*)d_ws;
    f16*   XCf   = (f16*)(ws + O_XC);
    f16*   W1f   = (f16*)(ws + O_W1);
    f16*   Whhf  = (f16*)(ws + O_WHH);
    f16*   W2f   = (f16*)(ws + O_W2);
    float* G     = (float*)(ws + O_G);
    ull*   pring = (ull*)(ws + O_PRING);

    // zero the packed ring: gens=0 (t=0 passes immediately), h=0 (= initial state)
    hipMemsetAsync(pring, 0, RING * 256 * sizeof(ull), stream);

    conv_xc<<<32768, 256, 0, stream>>>(x, hi, XCf);
    conv_w1<<<4096, 256, 0, stream>>>(W_ih, W1f);
    conv_wc<<<1024, 256, 0, stream>>>(W_hh, W_ih, Whhf, W2f);
    gemm_pre<<<dim3(16, 128), 256, 0, stream>>>(XCf, W1f, b_ih, b_hh, G);
    lstm_chain<<<NWG, 512, 0, stream>>>(G, Whhf, W2f, pring, (float*)d_out);
}

// Round 4
// 29487.784 us; speedup vs baseline: 2.3054x; 2.3054x over previous
//
#include <hip/hip_runtime.h>

typedef _Float16 f16;
typedef _Float16 f16x2 __attribute__((ext_vector_type(2)));
typedef _Float16 f16x4 __attribute__((ext_vector_type(4)));
typedef _Float16 f16x8 __attribute__((ext_vector_type(8)));
typedef float f32x4 __attribute__((ext_vector_type(4)));
typedef unsigned int u32;
typedef unsigned int u32x4 __attribute__((ext_vector_type(4)));
typedef unsigned long long ull;

#define HD 512
#define T_TOT 16384
#define RING 128
#define NWG 32
#define NTH 576          // 9 waves: 8 dot + 1 poll/cell

// ---------------- ws layout (bytes) ----------------
static const size_t O_XC    = 0;                       // 16384*2048 f16  = 64MB
static const size_t O_W1    = 67108864;                // 2048*2048 f16   = 8MB
static const size_t O_WHH   = 75497472;                // 2048*512 f16    = 2MB
static const size_t O_W2    = 77594624;                // 2048*512 f16    = 2MB
static const size_t O_G     = 79691776;                // 16384*2048 f32  = 128MB
static const size_t O_PRING = 213909504;               // 128*256 ull     = 256KB

__device__ __forceinline__ float dot2f(f16x2 a, f16x2 b, float c) {
#if __has_builtin(__builtin_amdgcn_fdot2)
    return __builtin_amdgcn_fdot2(a, b, c, false);
#else
    return fmaf((float)a[0], (float)b[0], fmaf((float)a[1], (float)b[1], c));
#endif
}
__device__ __forceinline__ f16x2 bcf(u32 u) { return __builtin_bit_cast(f16x2, u); }

__device__ __forceinline__ float sigf(float x) {
    return __frcp_rn(1.0f + __expf(-x));
}
__device__ __forceinline__ float tanhfast(float x) {
    return 1.0f - 2.0f * __frcp_rn(__expf(2.0f * x) + 1.0f);
}

// relaxed agent-scope (to L3 coherence point, no inv/wb fences)
__device__ __forceinline__ ull ld_a64(const ull* p) {
    return __hip_atomic_load(p, __ATOMIC_RELAXED, __HIP_MEMORY_SCOPE_AGENT);
}
__device__ __forceinline__ void st_a64(ull* p, ull v) {
    __hip_atomic_store(p, v, __ATOMIC_RELAXED, __HIP_MEMORY_SCOPE_AGENT);
}

// ---------- convert x,hi -> XC f16 [t=s*64+b][k 0..2048) ----------
__global__ __launch_bounds__(256) void conv_xc(const float* __restrict__ x,
                                               const float* __restrict__ hi,
                                               f16* __restrict__ xc) {
    int gid = blockIdx.x * 256 + threadIdx.x;
    int t = gid >> 9;
    int k = (gid & 511) << 2;
    int b = t & 63, s = t >> 6;
    const float* src = (k < 1024) ? (x  + ((size_t)((b << 8) + s) << 10) + k)
                                  : (hi + ((size_t)((b << 8) + s) << 10) + (k - 1024));
    float4 v = *reinterpret_cast<const float4*>(src);
    f16x4 o = { (_Float16)v.x, (_Float16)v.y, (_Float16)v.z, (_Float16)v.w };
    *reinterpret_cast<f16x4*>(xc + ((size_t)t << 11) + k) = o;
}

// ---------- convert W_ih[:, :2048] -> W1 f16 row-major ----------
__global__ __launch_bounds__(256) void conv_w1(const float* __restrict__ wih,
                                               f16* __restrict__ w1) {
    int gid = blockIdx.x * 256 + threadIdx.x;
    int j = gid >> 9;
    int k = (gid & 511) << 2;
    float4 v = *reinterpret_cast<const float4*>(wih + (size_t)j * 2560 + k);
    f16x4 o = { (_Float16)v.x, (_Float16)v.y, (_Float16)v.z, (_Float16)v.w };
    *reinterpret_cast<f16x4*>(w1 + ((size_t)j << 11) + k) = o;
}

// ---------- convert W_hh and W_ih[:, 2048:2560] -> f16 ----------
__global__ __launch_bounds__(256) void conv_wc(const float* __restrict__ whh,
                                               const float* __restrict__ wih,
                                               f16* __restrict__ whhf,
                                               f16* __restrict__ w2f) {
    int gid = blockIdx.x * 256 + threadIdx.x;
    int j = gid >> 7;
    int k = (gid & 127) << 2;
    float4 a = *reinterpret_cast<const float4*>(whh + (size_t)j * 512 + k);
    f16x4 oa = { (_Float16)a.x, (_Float16)a.y, (_Float16)a.z, (_Float16)a.w };
    *reinterpret_cast<f16x4*>(whhf + ((size_t)j << 9) + k) = oa;
    float4 bv = *reinterpret_cast<const float4*>(wih + (size_t)j * 2560 + 2048 + k);
    f16x4 ob = { (_Float16)bv.x, (_Float16)bv.y, (_Float16)bv.z, (_Float16)bv.w };
    *reinterpret_cast<f16x4*>(w2f + ((size_t)j << 9) + k) = ob;
}

// ---------- G = XC @ W1^T + (b_ih+b_hh), f16 MFMA ----------
__global__ __launch_bounds__(256) void gemm_pre(const f16* __restrict__ XC,
                                                const f16* __restrict__ W1,
                                                const float* __restrict__ b_ih,
                                                const float* __restrict__ b_hh,
                                                float* __restrict__ G) {
    int w = threadIdx.x >> 6, l = threadIdx.x & 63;
    int R0 = blockIdx.y * 128 + (w >> 1) * 64;
    int C0 = blockIdx.x * 128 + (w & 1) * 64;
    int lr = l & 15, kb = l >> 4;
    f32x4 acc[4][4] = {};
    const f16* Abase = XC + (size_t)(R0 + lr) * 2048 + kb * 8;
    const f16* Bbase = W1 + (size_t)(C0 + lr) * 2048 + kb * 8;
    for (int kk = 0; kk < 2048; kk += 32) {
        f16x8 av[4], bv[4];
#pragma unroll
        for (int i = 0; i < 4; i++)
            av[i] = *reinterpret_cast<const f16x8*>(Abase + (size_t)(i * 16) * 2048 + kk);
#pragma unroll
        for (int i = 0; i < 4; i++)
            bv[i] = *reinterpret_cast<const f16x8*>(Bbase + (size_t)(i * 16) * 2048 + kk);
#pragma unroll
        for (int fr = 0; fr < 4; fr++)
#pragma unroll
            for (int fc = 0; fc < 4; fc++)
                acc[fr][fc] = __builtin_amdgcn_mfma_f32_16x16x32_f16(av[fr], bv[fc], acc[fr][fc], 0, 0, 0);
    }
#pragma unroll
    for (int fc = 0; fc < 4; fc++) {
        int col = C0 + fc * 16 + lr;
        float bias = b_ih[col] + b_hh[col];
#pragma unroll
        for (int fr = 0; fr < 4; fr++) {
#pragma unroll
            for (int r = 0; r < 4; r++) {
                int row = R0 + fr * 16 + kb * 4 + r;
                G[(size_t)row * 2048 + col] = acc[fr][fc][r] + bias;
            }
        }
    }
}

// ---------- sequential chain: 32 WGs x 576 threads (8 dot waves + 1 poll/cell) ----------
// Global ring slot = 256 ull, ull j = [tag32 | h(2j+1) | h(2j)].
// LDS hist: 128 slots x 512 f16 (uint4 chunks of 8 h) — W2 reads h[t-64], Whh reads h[t-1].
// Dot wave wv in [0,8): gate g=wv&3, half uh=wv>>2; lane l = k-slice h[8l..8l+8);
// per-lane 8 rows (units uh*8..+8), weights 2x32 pinned VGPRs.
__global__ __launch_bounds__(NTH, 1) void lstm_chain(const float* __restrict__ G,
                                                     const f16* __restrict__ Whhf,
                                                     const f16* __restrict__ W2f,
                                                     ull* __restrict__ ring,
                                                     float* __restrict__ out) {
    const int wg = blockIdx.x;
    const int tid = threadIdx.x;
    const int wv = tid >> 6, l = tid & 63;

    __shared__ u32x4 hist[RING][64];          // 128KB
    __shared__ float part[2][4][16];

    // zero hist slots 64..127 (the h[t<0]=0 reads for W2); slots 0..63 written before read
    for (int i = tid; i < 64 * 64; i += NTH)
        hist[64 + (i >> 6)][i & 63] = (u32x4){0u, 0u, 0u, 0u};

    // ---- dot-wave init: load + pin weights ----
    u32 wu1[32], wu2[32];
    if (wv < 8) {
        const int g = wv & 3, uh = wv >> 2;
        const int row0 = g * 512 + wg * 16 + uh * 8;
#pragma unroll
        for (int r = 0; r < 8; r++) {
            f16x8 v1 = *reinterpret_cast<const f16x8*>(Whhf + (size_t)(row0 + r) * 512 + 8 * l);
            f16x8 v2 = *reinterpret_cast<const f16x8*>(W2f  + (size_t)(row0 + r) * 512 + 8 * l);
            u32x4 a = __builtin_bit_cast(u32x4, v1);
            u32x4 b = __builtin_bit_cast(u32x4, v2);
            wu1[r * 4 + 0] = a.x; wu1[r * 4 + 1] = a.y; wu1[r * 4 + 2] = a.z; wu1[r * 4 + 3] = a.w;
            wu2[r * 4 + 0] = b.x; wu2[r * 4 + 1] = b.y; wu2[r * 4 + 2] = b.z; wu2[r * 4 + 3] = b.w;
        }
#pragma unroll
        for (int i = 0; i < 32; i++) {
            asm volatile("" : "+v"(wu1[i]));
            asm volatile("" : "+v"(wu2[i]));
        }
    }

    const int g = wv & 3, uh = wv >> 2;
    const int grow = (l >> 4) * 512 + wg * 16 + (l & 15);   // poller's G row
    float gval = 0.0f, cst = 0.0f;
    if (wv == 8) gval = G[grow];                             // G[t=0]
    __syncthreads();

    for (int t = 0; t < T_TOT; t++) {
        const int buf = t & 1;
        const int sA = (t + 64) & (RING - 1);   // h[t-64]
        const int sB = (t - 1) & (RING - 1);    // h[t-1]
        const int sW = t & (RING - 1);

        float a[8] = {0.f, 0.f, 0.f, 0.f, 0.f, 0.f, 0.f, 0.f};
        float gn = gval;

        if (wv < 8) {
            // ---- phase A: W2 . h[t-64] from LDS (always ready) ----
            u32x4 ch = hist[sA][l];
            f16x2 h0 = bcf(ch.x), h1 = bcf(ch.y), h2 = bcf(ch.z), h3 = bcf(ch.w);
#pragma unroll
            for (int r = 0; r < 8; r++) {
                a[r] = dot2f(bcf(wu2[r * 4 + 0]), h0, a[r]);
                a[r] = dot2f(bcf(wu2[r * 4 + 1]), h1, a[r]);
                a[r] = dot2f(bcf(wu2[r * 4 + 2]), h2, a[r]);
                a[r] = dot2f(bcf(wu2[r * 4 + 3]), h3, a[r]);
            }
        } else {
            // ---- poller: prefetch G[t+1], then poll h[t-1] tags, repack to LDS ----
            int tn = (t + 1 < T_TOT) ? t + 1 : t;
            gn = G[(size_t)tn * 2048 + grow];
            const ull* base = ring + (size_t)sB * 256 + 4 * l;
            const u32 want = (u32)t;
            ull v0, v1, v2, v3;
            while (true) {
                v0 = ld_a64(base + 0);
                v1 = ld_a64(base + 1);
                v2 = ld_a64(base + 2);
                v3 = ld_a64(base + 3);
                u32 x = ((u32)(v0 >> 32) ^ want) | ((u32)(v1 >> 32) ^ want) |
                        ((u32)(v2 >> 32) ^ want) | ((u32)(v3 >> 32) ^ want);
                if (__all(x == 0)) break;
            }
            hist[sB][l] = (u32x4){(u32)v0, (u32)v1, (u32)v2, (u32)v3};
        }
        __syncthreads();

        if (wv < 8) {
            // ---- phase B: Whh . h[t-1] from LDS ----
            u32x4 ch = hist[sB][l];
            f16x2 h0 = bcf(ch.x), h1 = bcf(ch.y), h2 = bcf(ch.z), h3 = bcf(ch.w);
#pragma unroll
            for (int r = 0; r < 8; r++) {
                a[r] = dot2f(bcf(wu1[r * 4 + 0]), h0, a[r]);
                a[r] = dot2f(bcf(wu1[r * 4 + 1]), h1, a[r]);
                a[r] = dot2f(bcf(wu1[r * 4 + 2]), h2, a[r]);
                a[r] = dot2f(bcf(wu1[r * 4 + 3]), h3, a[r]);
            }
            // ---- recursive-halving reduce over 64 lanes, 8 rows -> 1 row/lane ----
            const bool s0 = l & 1, s1 = l & 2, s2 = l & 4;
            float b4_0 = (s0 ? a[4] : a[0]) + __shfl_xor((s0 ? a[0] : a[4]), 1);
            float b4_1 = (s0 ? a[5] : a[1]) + __shfl_xor((s0 ? a[1] : a[5]), 1);
            float b4_2 = (s0 ? a[6] : a[2]) + __shfl_xor((s0 ? a[2] : a[6]), 1);
            float b4_3 = (s0 ? a[7] : a[3]) + __shfl_xor((s0 ? a[3] : a[7]), 1);
            float c2_0 = (s1 ? b4_2 : b4_0) + __shfl_xor((s1 ? b4_0 : b4_2), 2);
            float c2_1 = (s1 ? b4_3 : b4_1) + __shfl_xor((s1 ? b4_1 : b4_3), 2);
            float d    = (s2 ? c2_1 : c2_0) + __shfl_xor((s2 ? c2_0 : c2_1), 4);
            d += __shfl_xor(d, 8);
            d += __shfl_xor(d, 16);
            d += __shfl_xor(d, 32);
            if (l < 8) {
                int rr = ((l & 1) << 2) | (l & 2) | ((l >> 2) & 1);   // bitrev3
                part[buf][g][uh * 8 + rr] = d;
            }
        }
        __syncthreads();

        if (wv == 8) {
            // ---- cell + publish ----
            int gg = l >> 4, uu = l & 15;
            float val = part[buf][gg][uu] + gval;
            float act = (gg == 2) ? tanhfast(val) : sigf(val);
            float fi = __shfl(act, uu);
            float ff = __shfl(act, uu + 16);
            float fg = __shfl(act, uu + 32);
            float fo = __shfl(act, uu + 48);
            cst = ff * cst + fi * fg;
            float h = fo * tanhfast(cst);
            u32 hb = (u32)__builtin_bit_cast(unsigned short, (f16)h);
            u32 plo = (u32)__shfl((int)hb, 2 * (l & 7));
            u32 phi = (u32)__shfl((int)hb, 2 * (l & 7) + 1);
            ull pv = (ull)(plo & 0xffffu) | ((ull)(phi & 0xffffu) << 16) |
                     ((ull)(u32)(t + 1) << 32);
            if (l < 8)
                st_a64(ring + (size_t)sW * 256 + wg * 8 + l, pv);
            if (l < 16) {
                int b = t & 63, s = t >> 6;
                out[((size_t)((b << 8) + s)) * 512 + wg * 16 + l] = h;
            }
        }
        gval = gn;
    }
}

extern "C" void kernel_launch(void* const* d_in, const int* in_sizes, int n_in,
                              void* d_out, int out_size, void* d_ws, size_t ws_size,
                              hipStream_t stream) {
    const float* x    = (const float*)d_in[0];
    const float* hi   = (const float*)d_in[1];
    const float* W_ih = (const float*)d_in[2];
    const float* W_hh = (const float*)d_in[3];
    const float* b_ih = (const float*)d_in[4];
    const float* b_hh = (const float*)d_in[5];

    char* ws = (char*)d_ws;
    f16*   XCf   = (f16*)(ws + O_XC);
    f16*   W1f   = (f16*)(ws + O_W1);
    f16*   Whhf  = (f16*)(ws + O_WHH);
    f16*   W2f   = (f16*)(ws + O_W2);
    float* G     = (float*)(ws + O_G);
    ull*   ring  = (ull*)(ws + O_PRING);

    // zero the ring every launch: slot 127 tag 0 == t=0's wanted gen, h=0 initial state
    hipMemsetAsync(ring, 0, (size_t)RING * 256 * sizeof(ull), stream);

    conv_xc<<<32768, 256, 0, stream>>>(x, hi, XCf);
    conv_w1<<<4096, 256, 0, stream>>>(W_ih, W1f);
    conv_wc<<<1024, 256, 0, stream>>>(W_hh, W_ih, Whhf, W2f);
    gemm_pre<<<dim3(16, 128), 256, 0, stream>>>(XCf, W1f, b_ih, b_hh, G);
    lstm_chain<<<NWG, NTH, 0, stream>>>(G, Whhf, W2f, ring, (float*)d_out);
}